// Round 1
// baseline (1007.024 us; speedup 1.0000x reference)
//
#include <hip/hip_runtime.h>
#include <hip/hip_bf16.h>

#define HIDDEN 1024
#define INTER 2048
#define NE 8
#define GS 128
#define TOKENS 4096
#define MAXROWS 8704  // 8192 routed rows + 8*64 padding capacity

typedef __bf16 bf16x8 __attribute__((ext_vector_type(8)));
typedef float f32x4 __attribute__((ext_vector_type(4)));

// ---- ws layout (bytes) ----
#define OFF_TOPKI 0u               // int[4096][2]
#define OFF_TOPKW 32768u           // float[4096][2]
#define OFF_CTRL  65536u           // int[32]: [0..7]=counts [8..15]=fill [16..23]=offsets [24]=total
#define OFF_TOK   65792u           // int[MAXROWS]
#define OFF_GATE  100608u          // float[MAXROWS]
#define OFF_XG    135424u          // bf16[MAXROWS][HIDDEN]      (17.8 MB)
#define OFF_A     17961216u        // bf16[MAXROWS][INTER]       (35.7 MB)
#define OFF_W1D   53612800u        // bf16[NE][4096][HIDDEN]     (67.1 MB)
#define OFF_W2D   120721664u       // bf16[NE][1024][INTER]      (33.6 MB)

__device__ __forceinline__ unsigned short f2bf(float f) {
  union { float f; unsigned int u; } v; v.f = f;
  unsigned int r = (v.u + 0x7FFFu + ((v.u >> 16) & 1u)) >> 16;
  return (unsigned short)r;
}
__device__ __forceinline__ unsigned int pack2(unsigned short lo, unsigned short hi) {
  return (unsigned int)lo | ((unsigned int)hi << 16);
}

// ---------------- router: scores = x @ rw^T, top-2 + softmax ----------------
__global__ __launch_bounds__(256) void k_router(const float* __restrict__ x,
    const float* __restrict__ rw, int* __restrict__ ctrl,
    int* __restrict__ topki, float* __restrict__ topkw) {
  int wave = threadIdx.x >> 6, lane = threadIdx.x & 63;
  int t = blockIdx.x * 4 + wave;
  float acc[NE];
#pragma unroll
  for (int e = 0; e < NE; e++) acc[e] = 0.f;
  const float* xr = x + (size_t)t * HIDDEN;
  for (int i = lane; i < HIDDEN; i += 64) {
    float xv = xr[i];
#pragma unroll
    for (int e = 0; e < NE; e++) acc[e] += xv * rw[e * HIDDEN + i];
  }
#pragma unroll
  for (int e = 0; e < NE; e++) {
    float v = acc[e];
    for (int off = 32; off > 0; off >>= 1) v += __shfl_down(v, off, 64);
    acc[e] = v;
  }
  if (lane == 0) {
    int b0 = 0; float s0 = acc[0];
#pragma unroll
    for (int e = 1; e < NE; e++) if (acc[e] > s0) { s0 = acc[e]; b0 = e; }
    int b1 = -1; float s1 = -3.0e38f;
#pragma unroll
    for (int e = 0; e < NE; e++) if (e != b0 && acc[e] > s1) { s1 = acc[e]; b1 = e; }
    float w0 = 1.f / (1.f + __expf(s1 - s0));
    topki[t * 2] = b0; topki[t * 2 + 1] = b1;
    topkw[t * 2] = w0; topkw[t * 2 + 1] = 1.f - w0;
    atomicAdd(&ctrl[b0], 1);
    atomicAdd(&ctrl[b1], 1);
  }
}

// --------------- offsets (padded to 64) + pad slot marking -----------------
__global__ void k_offsets(int* __restrict__ ctrl, int* __restrict__ tok) {
  if (threadIdx.x == 0) {
    int run = 0;
    for (int e = 0; e < NE; e++) {
      int c = ctrl[e];
      int pc = (c + 63) & ~63;
      ctrl[16 + e] = run;
      for (int i = c; i < pc; i++) tok[run + i] = -1;
      run += pc;
    }
    ctrl[24] = run;
  }
}

// --------------- scatter token ids into expert lists ----------------------
__global__ __launch_bounds__(256) void k_scatter(const int* __restrict__ topki,
    const float* __restrict__ topkw, int* __restrict__ ctrl,
    int* __restrict__ tok, float* __restrict__ gate) {
  int t = blockIdx.x * 256 + threadIdx.x;
#pragma unroll
  for (int k = 0; k < 2; k++) {
    int e = topki[t * 2 + k];
    int pos = atomicAdd(&ctrl[8 + e], 1);
    int s = ctrl[16 + e] + pos;
    tok[s] = t;
    gate[s] = topkw[t * 2 + k];
  }
}

// --------------- gather x rows (fp32 -> bf16), zero pad rows ---------------
__global__ __launch_bounds__(256) void k_gather(const float* __restrict__ x,
    const int* __restrict__ ctrl, const int* __restrict__ tok,
    unsigned short* __restrict__ xg) {
  int s = blockIdx.x;
  if (s >= ctrl[24]) return;
  int t = tok[s];
  int c = threadIdx.x * 4;
  unsigned short* dst = xg + (size_t)s * HIDDEN + c;
  if (t < 0) {
    uint2 z; z.x = 0u; z.y = 0u;
    *reinterpret_cast<uint2*>(dst) = z;
  } else {
    float4 v = *reinterpret_cast<const float4*>(x + (size_t)t * HIDDEN + c);
    uint2 o;
    o.x = pack2(f2bf(v.x), f2bf(v.y));
    o.y = pack2(f2bf(v.z), f2bf(v.w));
    *reinterpret_cast<uint2*>(dst) = o;
  }
}

// --------------- int4 dequant -> bf16 (generic for w1/w2) ------------------
// i32_log2: log2(int32s per row). scale_pr: scales per row. 64 int32 = one 128-group.
__global__ __launch_bounds__(256) void k_deq(const int* __restrict__ w,
    const float* __restrict__ sc, unsigned short* __restrict__ wd,
    int i32_log2, int scale_pr) {
  int gid = blockIdx.x * 256 + threadIdx.x;
  int i4 = gid * 4;
  int r = i4 >> i32_log2;
  int i = i4 & ((1 << i32_log2) - 1);
  float s = sc[r * scale_pr + (i >> 6)];
  int4 p = *reinterpret_cast<const int4*>(w + (size_t)i4);
  int pv[4] = { p.x, p.y, p.z, p.w };
  uint4 o;
  unsigned int ov[4];
#pragma unroll
  for (int j = 0; j < 4; j++) {
    float lo = (float)((pv[j] & 15) - 8) * s;
    float hi = (float)(((pv[j] >> 4) & 15) - 8) * s;
    ov[j] = pack2(f2bf(lo), f2bf(hi));
  }
  o.x = ov[0]; o.y = ov[1]; o.z = ov[2]; o.w = ov[3];
  *reinterpret_cast<uint4*>(wd + ((size_t)r << (i32_log2 + 1)) + 2 * i) = o;
}

// --------------- GEMM1: h = xg @ w1^T, fused silu(gate)*up -> a (bf16) -----
// block 256 = 4 waves; tile 64 rows x 64 gate-cols (+ same 64 up-cols)
__global__ __launch_bounds__(256) void k_gemm1(
    const unsigned short* __restrict__ xg, const unsigned short* __restrict__ w1d,
    const int* __restrict__ ctrl, unsigned short* __restrict__ a_out) {
  int e = blockIdx.z;
  int padcnt = (ctrl[e] + 63) & ~63;
  int mt = blockIdx.y;
  if (mt * 64 >= padcnt) return;
  int row0 = ctrl[16 + e] + mt * 64;
  int n0 = blockIdx.x * 64;
  int lane = threadIdx.x & 63;
  int wave = threadIdx.x >> 6;
  int ln = lane & 15, quad = lane >> 4;
  int nw = n0 + wave * 16;

  const unsigned short* aptr = xg + (size_t)(row0 + ln) * HIDDEN + quad * 8;
  const unsigned short* bg = w1d + ((size_t)e * 4096 + nw + ln) * HIDDEN + quad * 8;
  const unsigned short* bu = bg + (size_t)INTER * HIDDEN;

  f32x4 accG[4] = {}, accU[4] = {};
#pragma unroll 2
  for (int k0 = 0; k0 < HIDDEN; k0 += 32) {
    bf16x8 af[4], bgf, buf_;
#pragma unroll
    for (int m = 0; m < 4; m++)
      af[m] = *reinterpret_cast<const bf16x8*>(aptr + (size_t)m * 16 * HIDDEN + k0);
    bgf = *reinterpret_cast<const bf16x8*>(bg + k0);
    buf_ = *reinterpret_cast<const bf16x8*>(bu + k0);
#pragma unroll
    for (int m = 0; m < 4; m++) {
      accG[m] = __builtin_amdgcn_mfma_f32_16x16x32_bf16(af[m], bgf, accG[m], 0, 0, 0);
      accU[m] = __builtin_amdgcn_mfma_f32_16x16x32_bf16(af[m], buf_, accU[m], 0, 0, 0);
    }
  }
  int col = nw + ln;
#pragma unroll
  for (int m = 0; m < 4; m++) {
#pragma unroll
    for (int r = 0; r < 4; r++) {
      float g = accG[m][r], u = accU[m][r];
      float act = (g / (1.f + __expf(-g))) * u;
      int row = row0 + m * 16 + quad * 4 + r;
      a_out[(size_t)row * INTER + col] = f2bf(act);
    }
  }
}

// --------------- GEMM2: y = a @ w2^T, gated atomic scatter into out --------
__global__ __launch_bounds__(256) void k_gemm2(
    const unsigned short* __restrict__ a_in, const unsigned short* __restrict__ w2d,
    const int* __restrict__ ctrl, const int* __restrict__ tok,
    const float* __restrict__ gate, float* __restrict__ out) {
  __shared__ int stok[64];
  __shared__ float sgate[64];
  int e = blockIdx.z;
  int padcnt = (ctrl[e] + 63) & ~63;
  int mt = blockIdx.y;
  if (mt * 64 >= padcnt) return;
  int row0 = ctrl[16 + e] + mt * 64;
  if (threadIdx.x < 64) {
    stok[threadIdx.x] = tok[row0 + threadIdx.x];
    sgate[threadIdx.x] = gate[row0 + threadIdx.x];
  }
  __syncthreads();
  int n0 = blockIdx.x * 64;
  int lane = threadIdx.x & 63;
  int wave = threadIdx.x >> 6;
  int ln = lane & 15, quad = lane >> 4;
  int nw = n0 + wave * 16;

  const unsigned short* aptr = a_in + (size_t)(row0 + ln) * INTER + quad * 8;
  const unsigned short* bp = w2d + ((size_t)e * 1024 + nw + ln) * INTER + quad * 8;

  f32x4 acc[4] = {};
#pragma unroll 2
  for (int k0 = 0; k0 < INTER; k0 += 32) {
    bf16x8 af[4], bf_;
#pragma unroll
    for (int m = 0; m < 4; m++)
      af[m] = *reinterpret_cast<const bf16x8*>(aptr + (size_t)m * 16 * INTER + k0);
    bf_ = *reinterpret_cast<const bf16x8*>(bp + k0);
#pragma unroll
    for (int m = 0; m < 4; m++)
      acc[m] = __builtin_amdgcn_mfma_f32_16x16x32_bf16(af[m], bf_, acc[m], 0, 0, 0);
  }
  int col = nw + ln;
#pragma unroll
  for (int m = 0; m < 4; m++) {
#pragma unroll
    for (int r = 0; r < 4; r++) {
      int rl = m * 16 + quad * 4 + r;
      int t = stok[rl];
      if (t >= 0) atomicAdd(out + (size_t)t * HIDDEN + col, sgate[rl] * acc[m][r]);
    }
  }
}

extern "C" void kernel_launch(void* const* d_in, const int* in_sizes, int n_in,
                              void* d_out, int out_size, void* d_ws, size_t ws_size,
                              hipStream_t stream) {
  const float* x   = (const float*)d_in[0];
  const float* rw  = (const float*)d_in[1];
  const int*   w1  = (const int*)d_in[2];
  const float* w1s = (const float*)d_in[3];
  const int*   w2  = (const int*)d_in[4];
  const float* w2s = (const float*)d_in[5];
  float* out = (float*)d_out;
  char* ws = (char*)d_ws;

  int*   topki = (int*)(ws + OFF_TOPKI);
  float* topkw = (float*)(ws + OFF_TOPKW);
  int*   ctrl  = (int*)(ws + OFF_CTRL);
  int*   tok   = (int*)(ws + OFF_TOK);
  float* gate  = (float*)(ws + OFF_GATE);
  unsigned short* xg  = (unsigned short*)(ws + OFF_XG);
  unsigned short* a   = (unsigned short*)(ws + OFF_A);
  unsigned short* w1d = (unsigned short*)(ws + OFF_W1D);
  unsigned short* w2d = (unsigned short*)(ws + OFF_W2D);

  hipMemsetAsync(ctrl, 0, 128, stream);
  k_router<<<TOKENS / 4, 256, 0, stream>>>(x, rw, ctrl, topki, topkw);
  k_offsets<<<1, 64, 0, stream>>>(ctrl, tok);
  k_scatter<<<TOKENS / 256, 256, 0, stream>>>(topki, topkw, ctrl, tok, gate);
  k_gather<<<MAXROWS, 256, 0, stream>>>(x, ctrl, tok, xg);
  // w1: 8*4096 rows * 512 int32 -> 16384 blocks ; w2: 8*1024 rows * 1024 int32 -> 8192 blocks
  k_deq<<<16384, 256, 0, stream>>>(w1, w1s, w1d, 9, 8);
  k_deq<<<8192, 256, 0, stream>>>(w2, w2s, w2d, 10, 16);
  hipMemsetAsync(out, 0, (size_t)out_size * sizeof(float), stream);
  dim3 g1(INTER / 64, 64, NE);
  k_gemm1<<<g1, 256, 0, stream>>>(xg, w1d, ctrl, a);
  dim3 g2(HIDDEN / 64, 64, NE);
  k_gemm2<<<g2, 256, 0, stream>>>(a, w2d, ctrl, tok, gate, out);
}

// Round 2
// 495.434 us; speedup vs baseline: 2.0326x; 2.0326x over previous
//
#include <hip/hip_runtime.h>
#include <hip/hip_bf16.h>

#define HIDDEN 1024
#define INTER 2048
#define NE 8
#define GS 128
#define TOKENS 4096
#define MAXROWS 9216  // 8192 routed rows + 8*128 padding capacity

typedef __bf16 bf16x8 __attribute__((ext_vector_type(8)));
typedef float f32x4 __attribute__((ext_vector_type(4)));

// ---- ws layout (bytes) ----
#define OFF_TOPKI 0u               // int[4096][2]
#define OFF_TOPKW 32768u           // float[4096][2]
#define OFF_CTRL  65536u           // int[32]: [0..7]=counts [8..15]=fill [16..23]=offsets [24]=total
#define OFF_TOK   66048u           // int[MAXROWS]            -> 102912
#define OFF_GATE  102912u          // float[MAXROWS]          -> 139776
#define OFF_XG    139776u          // bf16[MAXROWS][HIDDEN]   -> 19014144
#define OFF_A     19014144u       // bf16[MAXROWS][INTER]    -> 56762880
#define OFF_W1D   56762880u       // bf16[NE][4096][HIDDEN]  -> 123871744
#define OFF_W2D   123871744u      // bf16[NE][1024][INTER]   -> 157426176

__device__ __forceinline__ unsigned short f2bf(float f) {
  union { float f; unsigned int u; } v; v.f = f;
  unsigned int r = (v.u + 0x7FFFu + ((v.u >> 16) & 1u)) >> 16;
  return (unsigned short)r;
}
__device__ __forceinline__ unsigned int pack2(unsigned short lo, unsigned short hi) {
  return (unsigned int)lo | ((unsigned int)hi << 16);
}

// async global->LDS, 16B per lane. LDS dest must be wave-uniform base + lane*16.
typedef const __attribute__((address_space(1))) unsigned int GAS;
typedef __attribute__((address_space(3))) unsigned int LAS;
__device__ __forceinline__ void gload16(const unsigned short* g, unsigned short* l) {
  __builtin_amdgcn_global_load_lds((GAS*)g, (LAS*)l, 16, 0, 0);
}

// ---------------- router: scores = x @ rw^T, top-2 + softmax ----------------
__global__ __launch_bounds__(256) void k_router(const float* __restrict__ x,
    const float* __restrict__ rw, int* __restrict__ ctrl,
    int* __restrict__ topki, float* __restrict__ topkw) {
  int wave = threadIdx.x >> 6, lane = threadIdx.x & 63;
  int t = blockIdx.x * 4 + wave;
  float acc[NE];
#pragma unroll
  for (int e = 0; e < NE; e++) acc[e] = 0.f;
  const float* xr = x + (size_t)t * HIDDEN;
  for (int i = lane; i < HIDDEN; i += 64) {
    float xv = xr[i];
#pragma unroll
    for (int e = 0; e < NE; e++) acc[e] += xv * rw[e * HIDDEN + i];
  }
#pragma unroll
  for (int e = 0; e < NE; e++) {
    float v = acc[e];
    for (int off = 32; off > 0; off >>= 1) v += __shfl_down(v, off, 64);
    acc[e] = v;
  }
  if (lane == 0) {
    int b0 = 0; float s0 = acc[0];
#pragma unroll
    for (int e = 1; e < NE; e++) if (acc[e] > s0) { s0 = acc[e]; b0 = e; }
    int b1 = -1; float s1 = -3.0e38f;
#pragma unroll
    for (int e = 0; e < NE; e++) if (e != b0 && acc[e] > s1) { s1 = acc[e]; b1 = e; }
    float w0 = 1.f / (1.f + __expf(s1 - s0));
    topki[t * 2] = b0; topki[t * 2 + 1] = b1;
    topkw[t * 2] = w0; topkw[t * 2 + 1] = 1.f - w0;
    atomicAdd(&ctrl[b0], 1);
    atomicAdd(&ctrl[b1], 1);
  }
}

// --------------- offsets (padded to 128) + pad slot marking -----------------
__global__ void k_offsets(int* __restrict__ ctrl, int* __restrict__ tok) {
  if (threadIdx.x == 0) {
    int run = 0;
    for (int e = 0; e < NE; e++) {
      int c = ctrl[e];
      int pc = (c + 127) & ~127;
      ctrl[16 + e] = run;
      for (int i = c; i < pc; i++) tok[run + i] = -1;
      run += pc;
    }
    ctrl[24] = run;
  }
}

// --------------- scatter token ids into expert lists ----------------------
__global__ __launch_bounds__(256) void k_scatter(const int* __restrict__ topki,
    const float* __restrict__ topkw, int* __restrict__ ctrl,
    int* __restrict__ tok, float* __restrict__ gate) {
  int t = blockIdx.x * 256 + threadIdx.x;
#pragma unroll
  for (int k = 0; k < 2; k++) {
    int e = topki[t * 2 + k];
    int pos = atomicAdd(&ctrl[8 + e], 1);
    int s = ctrl[16 + e] + pos;
    tok[s] = t;
    gate[s] = topkw[t * 2 + k];
  }
}

// --------------- gather x rows (fp32 -> bf16), zero pad rows ---------------
__global__ __launch_bounds__(256) void k_gather(const float* __restrict__ x,
    const int* __restrict__ ctrl, const int* __restrict__ tok,
    unsigned short* __restrict__ xg) {
  int s = blockIdx.x;
  if (s >= ctrl[24]) return;
  int t = tok[s];
  int c = threadIdx.x * 4;
  unsigned short* dst = xg + (size_t)s * HIDDEN + c;
  if (t < 0) {
    uint2 z; z.x = 0u; z.y = 0u;
    *reinterpret_cast<uint2*>(dst) = z;
  } else {
    float4 v = *reinterpret_cast<const float4*>(x + (size_t)t * HIDDEN + c);
    uint2 o;
    o.x = pack2(f2bf(v.x), f2bf(v.y));
    o.y = pack2(f2bf(v.z), f2bf(v.w));
    *reinterpret_cast<uint2*>(dst) = o;
  }
}

// --------------- int4 dequant -> bf16 (generic for w1/w2) ------------------
__global__ __launch_bounds__(256) void k_deq(const int* __restrict__ w,
    const float* __restrict__ sc, unsigned short* __restrict__ wd,
    int i32_log2, int scale_pr) {
  int gid = blockIdx.x * 256 + threadIdx.x;
  int i4 = gid * 4;
  int r = i4 >> i32_log2;
  int i = i4 & ((1 << i32_log2) - 1);
  float s = sc[r * scale_pr + (i >> 6)];
  int4 p = *reinterpret_cast<const int4*>(w + (size_t)i4);
  int pv[4] = { p.x, p.y, p.z, p.w };
  uint4 o;
  unsigned int ov[4];
#pragma unroll
  for (int j = 0; j < 4; j++) {
    float lo = (float)((pv[j] & 15) - 8) * s;
    float hi = (float)(((pv[j] >> 4) & 15) - 8) * s;
    ov[j] = pack2(f2bf(lo), f2bf(hi));
  }
  o.x = ov[0]; o.y = ov[1]; o.z = ov[2]; o.w = ov[3];
  *reinterpret_cast<uint4*>(wd + ((size_t)r << (i32_log2 + 1)) + 2 * i) = o;
}

// --------------- GEMM1: h = xg @ w1^T, fused silu(gate)*up -> a (bf16) -----
// m97 structure: 128 rows x (64 gate + 64 up) cols, BK=32, async LDS staging.
// 4 waves; wave computes 64 rows x 32 cols of both gate & up (4m x 2n MFMA).
__global__ __launch_bounds__(256) void k_gemm1(
    const unsigned short* __restrict__ xg, const unsigned short* __restrict__ w1d,
    const int* __restrict__ ctrl, unsigned short* __restrict__ a_out) {
  __shared__ unsigned short sA[128 * 32];   // 8 KB
  __shared__ unsigned short sBg[64 * 32];   // 4 KB
  __shared__ unsigned short sBu[64 * 32];   // 4 KB
  int e = blockIdx.z;
  int padcnt = (ctrl[e] + 127) & ~127;
  int mt = blockIdx.y;
  if (mt * 128 >= padcnt) return;
  int row0 = ctrl[16 + e] + mt * 128;
  int n0 = blockIdx.x * 64;
  int tid = threadIdx.x;
  int wave = tid >> 6, lane = tid & 63;
  int ln = lane & 15, quad = lane >> 4;
  int wr = (wave & 1) * 64, wc = (wave >> 1) * 32;

  // staging: thread t loads 16B; row = t>>2, col8 = t&3  (row-major [row][32])
  int srow = tid >> 2, scol = (tid & 3) * 8;
  const unsigned short* gA0 = xg + (size_t)(row0 + srow) * HIDDEN + scol;
  const unsigned short* gA1 = gA0 + (size_t)64 * HIDDEN;
  const unsigned short* gBg = w1d + ((size_t)e * 4096 + n0 + srow) * HIDDEN + scol;
  const unsigned short* gBu = gBg + (size_t)INTER * HIDDEN;
  unsigned short* lA0 = sA + tid * 8;
  unsigned short* lA1 = sA + 64 * 32 + tid * 8;
  unsigned short* lBg = sBg + tid * 8;
  unsigned short* lBu = sBu + tid * 8;

  f32x4 aG[4][2] = {}, aU[4][2] = {};
  for (int k0 = 0; k0 < HIDDEN; k0 += 32) {
    __syncthreads();
    gload16(gA0 + k0, lA0);
    gload16(gA1 + k0, lA1);
    gload16(gBg + k0, lBg);
    gload16(gBu + k0, lBu);
    __syncthreads();  // drains vmcnt -> LDS valid
    bf16x8 af[4], bg[2], bu[2];
#pragma unroll
    for (int m = 0; m < 4; m++)
      af[m] = *reinterpret_cast<const bf16x8*>(&sA[(wr + m * 16 + ln) * 32 + quad * 8]);
#pragma unroll
    for (int n = 0; n < 2; n++) {
      bg[n] = *reinterpret_cast<const bf16x8*>(&sBg[(wc + n * 16 + ln) * 32 + quad * 8]);
      bu[n] = *reinterpret_cast<const bf16x8*>(&sBu[(wc + n * 16 + ln) * 32 + quad * 8]);
    }
#pragma unroll
    for (int m = 0; m < 4; m++)
#pragma unroll
      for (int n = 0; n < 2; n++) {
        aG[m][n] = __builtin_amdgcn_mfma_f32_16x16x32_bf16(af[m], bg[n], aG[m][n], 0, 0, 0);
        aU[m][n] = __builtin_amdgcn_mfma_f32_16x16x32_bf16(af[m], bu[n], aU[m][n], 0, 0, 0);
      }
  }
#pragma unroll
  for (int m = 0; m < 4; m++)
#pragma unroll
    for (int n = 0; n < 2; n++) {
      int col = n0 + wc + n * 16 + ln;
#pragma unroll
      for (int r = 0; r < 4; r++) {
        float g = aG[m][n][r], u = aU[m][n][r];
        float act = (g / (1.f + __expf(-g))) * u;
        int row = row0 + wr + m * 16 + quad * 4 + r;
        a_out[(size_t)row * INTER + col] = f2bf(act);
      }
    }
}

// --------------- GEMM2: y = a @ w2^T, gated atomic scatter into out --------
// 128x128 tile, BK=32; wave computes 64x64 (4m x 4n MFMA).
__global__ __launch_bounds__(256) void k_gemm2(
    const unsigned short* __restrict__ a_in, const unsigned short* __restrict__ w2d,
    const int* __restrict__ ctrl, const int* __restrict__ tok,
    const float* __restrict__ gate, float* __restrict__ out) {
  __shared__ unsigned short sA[128 * 32];   // 8 KB
  __shared__ unsigned short sB[128 * 32];   // 8 KB
  __shared__ int stok[128];
  __shared__ float sgate[128];
  int e = blockIdx.z;
  int padcnt = (ctrl[e] + 127) & ~127;
  int mt = blockIdx.y;
  if (mt * 128 >= padcnt) return;
  int row0 = ctrl[16 + e] + mt * 128;
  int n0 = blockIdx.x * 128;
  int tid = threadIdx.x;
  if (tid < 128) {
    stok[tid] = tok[row0 + tid];
    sgate[tid] = gate[row0 + tid];
  }
  int wave = tid >> 6, lane = tid & 63;
  int ln = lane & 15, quad = lane >> 4;
  int wr = (wave & 1) * 64, wc = (wave >> 1) * 64;

  int srow = tid >> 2, scol = (tid & 3) * 8;
  const unsigned short* gA0 = a_in + (size_t)(row0 + srow) * INTER + scol;
  const unsigned short* gA1 = gA0 + (size_t)64 * INTER;
  const unsigned short* gB0 = w2d + ((size_t)e * 1024 + n0 + srow) * INTER + scol;
  const unsigned short* gB1 = gB0 + (size_t)64 * INTER;
  unsigned short* lA0 = sA + tid * 8;
  unsigned short* lA1 = sA + 64 * 32 + tid * 8;
  unsigned short* lB0 = sB + tid * 8;
  unsigned short* lB1 = sB + 64 * 32 + tid * 8;

  f32x4 acc[4][4] = {};
  for (int k0 = 0; k0 < INTER; k0 += 32) {
    __syncthreads();
    gload16(gA0 + k0, lA0);
    gload16(gA1 + k0, lA1);
    gload16(gB0 + k0, lB0);
    gload16(gB1 + k0, lB1);
    __syncthreads();
    bf16x8 af[4], bf_[4];
#pragma unroll
    for (int m = 0; m < 4; m++)
      af[m] = *reinterpret_cast<const bf16x8*>(&sA[(wr + m * 16 + ln) * 32 + quad * 8]);
#pragma unroll
    for (int n = 0; n < 4; n++)
      bf_[n] = *reinterpret_cast<const bf16x8*>(&sB[(wc + n * 16 + ln) * 32 + quad * 8]);
#pragma unroll
    for (int m = 0; m < 4; m++)
#pragma unroll
      for (int n = 0; n < 4; n++)
        acc[m][n] = __builtin_amdgcn_mfma_f32_16x16x32_bf16(af[m], bf_[n], acc[m][n], 0, 0, 0);
  }
#pragma unroll
  for (int m = 0; m < 4; m++)
#pragma unroll
    for (int n = 0; n < 4; n++) {
      int col = n0 + wc + n * 16 + ln;
#pragma unroll
      for (int r = 0; r < 4; r++) {
        int rl = wr + m * 16 + quad * 4 + r;
        int t = stok[rl];
        if (t >= 0) atomicAdd(out + (size_t)t * HIDDEN + col, sgate[rl] * acc[m][n][r]);
      }
    }
}

extern "C" void kernel_launch(void* const* d_in, const int* in_sizes, int n_in,
                              void* d_out, int out_size, void* d_ws, size_t ws_size,
                              hipStream_t stream) {
  const float* x   = (const float*)d_in[0];
  const float* rw  = (const float*)d_in[1];
  const int*   w1  = (const int*)d_in[2];
  const float* w1s = (const float*)d_in[3];
  const int*   w2  = (const int*)d_in[4];
  const float* w2s = (const float*)d_in[5];
  float* out = (float*)d_out;
  char* ws = (char*)d_ws;

  int*   topki = (int*)(ws + OFF_TOPKI);
  float* topkw = (float*)(ws + OFF_TOPKW);
  int*   ctrl  = (int*)(ws + OFF_CTRL);
  int*   tok   = (int*)(ws + OFF_TOK);
  float* gate  = (float*)(ws + OFF_GATE);
  unsigned short* xg  = (unsigned short*)(ws + OFF_XG);
  unsigned short* a   = (unsigned short*)(ws + OFF_A);
  unsigned short* w1d = (unsigned short*)(ws + OFF_W1D);
  unsigned short* w2d = (unsigned short*)(ws + OFF_W2D);

  hipMemsetAsync(ctrl, 0, 128, stream);
  k_router<<<TOKENS / 4, 256, 0, stream>>>(x, rw, ctrl, topki, topkw);
  k_offsets<<<1, 64, 0, stream>>>(ctrl, tok);
  k_scatter<<<TOKENS / 256, 256, 0, stream>>>(topki, topkw, ctrl, tok, gate);
  k_gather<<<MAXROWS, 256, 0, stream>>>(x, ctrl, tok, xg);
  k_deq<<<16384, 256, 0, stream>>>(w1, w1s, w1d, 9, 8);
  k_deq<<<8192, 256, 0, stream>>>(w2, w2s, w2d, 10, 16);
  hipMemsetAsync(out, 0, (size_t)out_size * sizeof(float), stream);
  dim3 g1(INTER / 64, MAXROWS / 128, NE);
  k_gemm1<<<g1, 256, 0, stream>>>(xg, w1d, ctrl, a);
  dim3 g2(HIDDEN / 128, MAXROWS / 128, NE);
  k_gemm2<<<g2, 256, 0, stream>>>(a, w2d, ctrl, tok, gate, out);
}

// Round 3
// 477.060 us; speedup vs baseline: 2.1109x; 1.0385x over previous
//
#include <hip/hip_runtime.h>
#include <hip/hip_bf16.h>

#define HIDDEN 1024
#define INTER 2048
#define NE 8
#define GS 128
#define TOKENS 4096
#define MAXROWS 9216  // 8192 routed rows + 8*128 padding capacity

typedef __bf16 bf16x8 __attribute__((ext_vector_type(8)));
typedef float f32x4 __attribute__((ext_vector_type(4)));

// ---- ws layout (bytes) ----
#define OFF_TOPKI 0u               // int[4096][2]
#define OFF_TOPKW 32768u           // float[4096][2]
#define OFF_CTRL  65536u           // int[32]: [0..7]=counts [8..15]=fill [16..23]=offsets [24]=total
#define OFF_TOK   66048u           // int[MAXROWS]            -> 102912
#define OFF_SLOT  102912u          // int[TOKENS*2]           -> 135680
#define OFF_XG    139776u          // bf16[MAXROWS][HIDDEN]   (aliased as y after gemm1)
#define OFF_A     19014144u        // bf16[MAXROWS][INTER]
#define OFF_W1D   56762880u        // bf16[NE][4096][HIDDEN]
#define OFF_W2D   123871744u       // bf16[NE][1024][INTER]   -> 157426176 total

__device__ __forceinline__ unsigned short f2bf(float f) {
  union { float f; unsigned int u; } v; v.f = f;
  unsigned int r = (v.u + 0x7FFFu + ((v.u >> 16) & 1u)) >> 16;
  return (unsigned short)r;
}
__device__ __forceinline__ float bf2f(unsigned int u) {
  union { unsigned int u; float f; } v; v.u = u << 16;
  return v.f;
}
__device__ __forceinline__ unsigned int pack2(unsigned short lo, unsigned short hi) {
  return (unsigned int)lo | ((unsigned int)hi << 16);
}

// async global->LDS, 16B per lane. LDS dest is wave-uniform base + lane*16.
typedef const __attribute__((address_space(1))) unsigned int GAS;
typedef __attribute__((address_space(3))) unsigned int LAS;
__device__ __forceinline__ void gload16(const unsigned short* g, unsigned short* l) {
  __builtin_amdgcn_global_load_lds((GAS*)g, (LAS*)l, 16, 0, 0);
}

// XOR swizzle: LDS slot (row, cblk) holds global (row, cblk ^ ((row>>1)&3)).
// Read side: data (row, kblk) found at cblk = kblk ^ ((row>>1)&3).
// -> ds_read_b128 per quad covers all 8 16B-bank-groups exactly 2x (free).

// ---------------- router: scores = x @ rw^T, top-2 + softmax ----------------
__global__ __launch_bounds__(256) void k_router(const float* __restrict__ x,
    const float* __restrict__ rw, int* __restrict__ ctrl,
    int* __restrict__ topki, float* __restrict__ topkw) {
  int wave = threadIdx.x >> 6, lane = threadIdx.x & 63;
  int t = blockIdx.x * 4 + wave;
  float acc[NE];
#pragma unroll
  for (int e = 0; e < NE; e++) acc[e] = 0.f;
  const float* xr = x + (size_t)t * HIDDEN;
  for (int i = lane; i < HIDDEN; i += 64) {
    float xv = xr[i];
#pragma unroll
    for (int e = 0; e < NE; e++) acc[e] += xv * rw[e * HIDDEN + i];
  }
#pragma unroll
  for (int e = 0; e < NE; e++) {
    float v = acc[e];
    for (int off = 32; off > 0; off >>= 1) v += __shfl_down(v, off, 64);
    acc[e] = v;
  }
  if (lane == 0) {
    int b0 = 0; float s0 = acc[0];
#pragma unroll
    for (int e = 1; e < NE; e++) if (acc[e] > s0) { s0 = acc[e]; b0 = e; }
    int b1 = -1; float s1 = -3.0e38f;
#pragma unroll
    for (int e = 0; e < NE; e++) if (e != b0 && acc[e] > s1) { s1 = acc[e]; b1 = e; }
    float w0 = 1.f / (1.f + __expf(s1 - s0));
    topki[t * 2] = b0; topki[t * 2 + 1] = b1;
    topkw[t * 2] = w0; topkw[t * 2 + 1] = 1.f - w0;
    atomicAdd(&ctrl[b0], 1);
    atomicAdd(&ctrl[b1], 1);
  }
}

// --------------- offsets (padded to 128) + pad slot marking -----------------
__global__ void k_offsets(int* __restrict__ ctrl, int* __restrict__ tok) {
  if (threadIdx.x == 0) {
    int run = 0;
    for (int e = 0; e < NE; e++) {
      int c = ctrl[e];
      int pc = (c + 127) & ~127;
      ctrl[16 + e] = run;
      for (int i = c; i < pc; i++) tok[run + i] = -1;
      run += pc;
    }
    ctrl[24] = run;
  }
}

// --------------- scatter token ids into expert lists ----------------------
__global__ __launch_bounds__(256) void k_scatter(const int* __restrict__ topki,
    int* __restrict__ ctrl, int* __restrict__ tok, int* __restrict__ slots) {
  int t = blockIdx.x * 256 + threadIdx.x;
#pragma unroll
  for (int k = 0; k < 2; k++) {
    int e = topki[t * 2 + k];
    int pos = atomicAdd(&ctrl[8 + e], 1);
    int s = ctrl[16 + e] + pos;
    tok[s] = t;
    slots[t * 2 + k] = s;
  }
}

// --------------- gather x rows (fp32 -> bf16), zero pad rows ---------------
__global__ __launch_bounds__(256) void k_gather(const float* __restrict__ x,
    const int* __restrict__ ctrl, const int* __restrict__ tok,
    unsigned short* __restrict__ xg) {
  int s = blockIdx.x;
  if (s >= ctrl[24]) return;
  int t = tok[s];
  int c = threadIdx.x * 4;
  unsigned short* dst = xg + (size_t)s * HIDDEN + c;
  if (t < 0) {
    uint2 z; z.x = 0u; z.y = 0u;
    *reinterpret_cast<uint2*>(dst) = z;
  } else {
    float4 v = *reinterpret_cast<const float4*>(x + (size_t)t * HIDDEN + c);
    uint2 o;
    o.x = pack2(f2bf(v.x), f2bf(v.y));
    o.y = pack2(f2bf(v.z), f2bf(v.w));
    *reinterpret_cast<uint2*>(dst) = o;
  }
}

// --------------- int4 dequant -> bf16 (generic for w1/w2) ------------------
__global__ __launch_bounds__(256) void k_deq(const int* __restrict__ w,
    const float* __restrict__ sc, unsigned short* __restrict__ wd,
    int i32_log2, int scale_pr) {
  int gid = blockIdx.x * 256 + threadIdx.x;
  int i4 = gid * 4;
  int r = i4 >> i32_log2;
  int i = i4 & ((1 << i32_log2) - 1);
  float s = sc[r * scale_pr + (i >> 6)];
  int4 p = *reinterpret_cast<const int4*>(w + (size_t)i4);
  int pv[4] = { p.x, p.y, p.z, p.w };
  uint4 o;
  unsigned int ov[4];
#pragma unroll
  for (int j = 0; j < 4; j++) {
    float lo = (float)((pv[j] & 15) - 8) * s;
    float hi = (float)(((pv[j] >> 4) & 15) - 8) * s;
    ov[j] = pack2(f2bf(lo), f2bf(hi));
  }
  o.x = ov[0]; o.y = ov[1]; o.z = ov[2]; o.w = ov[3];
  *reinterpret_cast<uint4*>(wd + ((size_t)r << (i32_log2 + 1)) + 2 * i) = o;
}

// --------------- GEMM1: h = xg @ w1^T, fused silu(gate)*up -> a (bf16) -----
__global__ __launch_bounds__(256) void k_gemm1(
    const unsigned short* __restrict__ xg, const unsigned short* __restrict__ w1d,
    const int* __restrict__ ctrl, unsigned short* __restrict__ a_out) {
  __shared__ unsigned short sA[128 * 32];   // 8 KB
  __shared__ unsigned short sBg[64 * 32];   // 4 KB
  __shared__ unsigned short sBu[64 * 32];   // 4 KB
  int e = blockIdx.z;
  int padcnt = (ctrl[e] + 127) & ~127;
  int mt = blockIdx.y;
  if (mt * 128 >= padcnt) return;
  int row0 = ctrl[16 + e] + mt * 128;
  int n0 = blockIdx.x * 64;
  int tid = threadIdx.x;
  int wave = tid >> 6, lane = tid & 63;
  int ln = lane & 15, quad = lane >> 4;
  int wr = (wave & 1) * 64, wc = (wave >> 1) * 32;

  // staging: thread t owns LDS slot (row=t>>2, cblk=t&3); loads swizzled col.
  int srow = tid >> 2, scblk = tid & 3;
  int scol = (scblk ^ ((srow >> 1) & 3)) * 8;
  const unsigned short* gA0 = xg + (size_t)(row0 + srow) * HIDDEN + scol;
  const unsigned short* gA1 = gA0 + (size_t)64 * HIDDEN;
  const unsigned short* gBg = w1d + ((size_t)e * 4096 + n0 + srow) * HIDDEN + scol;
  const unsigned short* gBu = gBg + (size_t)INTER * HIDDEN;
  unsigned short* lA0 = sA + tid * 8;
  unsigned short* lA1 = sA + 64 * 32 + tid * 8;
  unsigned short* lBg = sBg + tid * 8;
  unsigned short* lBu = sBu + tid * 8;

  f32x4 aG[4][2] = {}, aU[4][2] = {};
  for (int k0 = 0; k0 < HIDDEN; k0 += 32) {
    __syncthreads();
    gload16(gA0 + k0, lA0);
    gload16(gA1 + k0, lA1);
    gload16(gBg + k0, lBg);
    gload16(gBu + k0, lBu);
    __syncthreads();
    bf16x8 af[4], bg[2], bu[2];
#pragma unroll
    for (int m = 0; m < 4; m++) {
      int ar = wr + m * 16 + ln;
      af[m] = *reinterpret_cast<const bf16x8*>(&sA[ar * 32 + (quad ^ ((ar >> 1) & 3)) * 8]);
    }
#pragma unroll
    for (int n = 0; n < 2; n++) {
      int br = wc + n * 16 + ln;
      int bo = br * 32 + (quad ^ ((br >> 1) & 3)) * 8;
      bg[n] = *reinterpret_cast<const bf16x8*>(&sBg[bo]);
      bu[n] = *reinterpret_cast<const bf16x8*>(&sBu[bo]);
    }
#pragma unroll
    for (int m = 0; m < 4; m++)
#pragma unroll
      for (int n = 0; n < 2; n++) {
        aG[m][n] = __builtin_amdgcn_mfma_f32_16x16x32_bf16(af[m], bg[n], aG[m][n], 0, 0, 0);
        aU[m][n] = __builtin_amdgcn_mfma_f32_16x16x32_bf16(af[m], bu[n], aU[m][n], 0, 0, 0);
      }
  }
#pragma unroll
  for (int m = 0; m < 4; m++)
#pragma unroll
    for (int n = 0; n < 2; n++) {
      int col = n0 + wc + n * 16 + ln;
#pragma unroll
      for (int r = 0; r < 4; r++) {
        float g = aG[m][n][r], u = aU[m][n][r];
        float act = (g / (1.f + __expf(-g))) * u;
        int row = row0 + wr + m * 16 + quad * 4 + r;
        a_out[(size_t)row * INTER + col] = f2bf(act);
      }
    }
}

// --------------- GEMM2: y[slot] = a @ w2^T (bf16, plain stores) ------------
__global__ __launch_bounds__(256) void k_gemm2(
    const unsigned short* __restrict__ a_in, const unsigned short* __restrict__ w2d,
    const int* __restrict__ ctrl, unsigned short* __restrict__ y) {
  __shared__ unsigned short sA[128 * 32];   // 8 KB
  __shared__ unsigned short sB[128 * 32];   // 8 KB
  int e = blockIdx.z;
  int padcnt = (ctrl[e] + 127) & ~127;
  int mt = blockIdx.y;
  if (mt * 128 >= padcnt) return;
  int row0 = ctrl[16 + e] + mt * 128;
  int n0 = blockIdx.x * 128;
  int tid = threadIdx.x;
  int wave = tid >> 6, lane = tid & 63;
  int ln = lane & 15, quad = lane >> 4;
  int wr = (wave & 1) * 64, wc = (wave >> 1) * 64;

  int srow = tid >> 2, scblk = tid & 3;
  int scol = (scblk ^ ((srow >> 1) & 3)) * 8;
  const unsigned short* gA0 = a_in + (size_t)(row0 + srow) * INTER + scol;
  const unsigned short* gA1 = gA0 + (size_t)64 * INTER;
  const unsigned short* gB0 = w2d + ((size_t)e * 1024 + n0 + srow) * INTER + scol;
  const unsigned short* gB1 = gB0 + (size_t)64 * INTER;
  unsigned short* lA0 = sA + tid * 8;
  unsigned short* lA1 = sA + 64 * 32 + tid * 8;
  unsigned short* lB0 = sB + tid * 8;
  unsigned short* lB1 = sB + 64 * 32 + tid * 8;

  f32x4 acc[4][4] = {};
  for (int k0 = 0; k0 < INTER; k0 += 32) {
    __syncthreads();
    gload16(gA0 + k0, lA0);
    gload16(gA1 + k0, lA1);
    gload16(gB0 + k0, lB0);
    gload16(gB1 + k0, lB1);
    __syncthreads();
    bf16x8 af[4], bf_[4];
#pragma unroll
    for (int m = 0; m < 4; m++) {
      int ar = wr + m * 16 + ln;
      af[m] = *reinterpret_cast<const bf16x8*>(&sA[ar * 32 + (quad ^ ((ar >> 1) & 3)) * 8]);
    }
#pragma unroll
    for (int n = 0; n < 4; n++) {
      int br = wc + n * 16 + ln;
      bf_[n] = *reinterpret_cast<const bf16x8*>(&sB[br * 32 + (quad ^ ((br >> 1) & 3)) * 8]);
    }
#pragma unroll
    for (int m = 0; m < 4; m++)
#pragma unroll
      for (int n = 0; n < 4; n++)
        acc[m][n] = __builtin_amdgcn_mfma_f32_16x16x32_bf16(af[m], bf_[n], acc[m][n], 0, 0, 0);
  }
#pragma unroll
  for (int m = 0; m < 4; m++)
#pragma unroll
    for (int n = 0; n < 4; n++) {
      int col = n0 + wc + n * 16 + ln;
#pragma unroll
      for (int r = 0; r < 4; r++) {
        int row = row0 + wr + m * 16 + quad * 4 + r;
        y[(size_t)row * HIDDEN + col] = f2bf(acc[m][n][r]);
      }
    }
}

// --------------- combine: out[t] = g0*y[s0] + g1*y[s1] ---------------------
__global__ __launch_bounds__(256) void k_combine(const unsigned short* __restrict__ y,
    const int* __restrict__ slots, const float* __restrict__ topkw,
    float* __restrict__ out) {
  int t = blockIdx.x;
  int c = threadIdx.x * 4;
  int s0 = slots[t * 2], s1 = slots[t * 2 + 1];
  float g0 = topkw[t * 2], g1 = topkw[t * 2 + 1];
  uint2 va = *reinterpret_cast<const uint2*>(y + (size_t)s0 * HIDDEN + c);
  uint2 vb = *reinterpret_cast<const uint2*>(y + (size_t)s1 * HIDDEN + c);
  float4 o;
  o.x = g0 * bf2f(va.x & 0xffffu) + g1 * bf2f(vb.x & 0xffffu);
  o.y = g0 * bf2f(va.x >> 16)     + g1 * bf2f(vb.x >> 16);
  o.z = g0 * bf2f(va.y & 0xffffu) + g1 * bf2f(vb.y & 0xffffu);
  o.w = g0 * bf2f(va.y >> 16)     + g1 * bf2f(vb.y >> 16);
  *reinterpret_cast<float4*>(out + (size_t)t * HIDDEN + c) = o;
}

extern "C" void kernel_launch(void* const* d_in, const int* in_sizes, int n_in,
                              void* d_out, int out_size, void* d_ws, size_t ws_size,
                              hipStream_t stream) {
  const float* x   = (const float*)d_in[0];
  const float* rw  = (const float*)d_in[1];
  const int*   w1  = (const int*)d_in[2];
  const float* w1s = (const float*)d_in[3];
  const int*   w2  = (const int*)d_in[4];
  const float* w2s = (const float*)d_in[5];
  float* out = (float*)d_out;
  char* ws = (char*)d_ws;

  int*   topki = (int*)(ws + OFF_TOPKI);
  float* topkw = (float*)(ws + OFF_TOPKW);
  int*   ctrl  = (int*)(ws + OFF_CTRL);
  int*   tok   = (int*)(ws + OFF_TOK);
  int*   slots = (int*)(ws + OFF_SLOT);
  unsigned short* xg  = (unsigned short*)(ws + OFF_XG);  // aliased as y after gemm1
  unsigned short* a   = (unsigned short*)(ws + OFF_A);
  unsigned short* w1d = (unsigned short*)(ws + OFF_W1D);
  unsigned short* w2d = (unsigned short*)(ws + OFF_W2D);

  hipMemsetAsync(ctrl, 0, 128, stream);
  k_router<<<TOKENS / 4, 256, 0, stream>>>(x, rw, ctrl, topki, topkw);
  k_offsets<<<1, 64, 0, stream>>>(ctrl, tok);
  k_scatter<<<TOKENS / 256, 256, 0, stream>>>(topki, ctrl, tok, slots);
  k_gather<<<MAXROWS, 256, 0, stream>>>(x, ctrl, tok, xg);
  k_deq<<<16384, 256, 0, stream>>>(w1, w1s, w1d, 9, 8);
  k_deq<<<8192, 256, 0, stream>>>(w2, w2s, w2d, 10, 16);
  dim3 g1(INTER / 64, MAXROWS / 128, NE);
  k_gemm1<<<g1, 256, 0, stream>>>(xg, w1d, ctrl, a);
  dim3 g2(HIDDEN / 128, MAXROWS / 128, NE);
  k_gemm2<<<g2, 256, 0, stream>>>(a, w2d, ctrl, xg /* y aliases xg */);
  k_combine<<<TOKENS, 256, 0, stream>>>(xg, slots, topkw, out);
}

// Round 4
// 337.788 us; speedup vs baseline: 2.9812x; 1.4123x over previous
//
#include <hip/hip_runtime.h>
#include <hip/hip_bf16.h>

#define HIDDEN 1024
#define INTER 2048
#define NE 8
#define GS 128
#define TOKENS 4096
#define MAXROWS 9216  // 8192 routed rows + 8*128 padding capacity

typedef __bf16 bf16x8 __attribute__((ext_vector_type(8)));
typedef float f32x4 __attribute__((ext_vector_type(4)));

// ---- ws layout (bytes) ----
#define OFF_TOPKI 0u               // int[4096][2]
#define OFF_TOPKW 32768u           // float[4096][2]
#define OFF_CTRL  65536u           // int[32]: [0..7]=counts [16..23]=offsets [24]=total
#define OFF_TOK   66048u           // int[MAXROWS]            -> 102912
#define OFF_SLOT  102912u          // int[TOKENS*2]           -> 135680
#define OFF_BC    135680u          // int[16][8] per-block expert counts
#define OFF_BASE  136192u          // int[16][8] per-block scatter bases
#define OFF_XG    139776u          // bf16[MAXROWS][HIDDEN]   (aliased as y after gemm1)
#define OFF_A     19014144u        // bf16[MAXROWS][INTER]
#define OFF_W1D   56762880u        // bf16[NE][4096][HIDDEN]
#define OFF_W2D   123871744u       // bf16[NE][1024][INTER]   -> 157426176 total

__device__ __forceinline__ unsigned short f2bf(float f) {
  union { float f; unsigned int u; } v; v.f = f;
  unsigned int r = (v.u + 0x7FFFu + ((v.u >> 16) & 1u)) >> 16;
  return (unsigned short)r;
}
__device__ __forceinline__ float bf2f(unsigned int u) {
  union { unsigned int u; float f; } v; v.u = u << 16;
  return v.f;
}
__device__ __forceinline__ unsigned int pack2(unsigned short lo, unsigned short hi) {
  return (unsigned int)lo | ((unsigned int)hi << 16);
}

// async global->LDS, 16B per lane. LDS dest is wave-uniform base + lane*16.
typedef const __attribute__((address_space(1))) unsigned int GAS;
typedef __attribute__((address_space(3))) unsigned int LAS;
__device__ __forceinline__ void gload16(const unsigned short* g, unsigned short* l) {
  __builtin_amdgcn_global_load_lds((GAS*)g, (LAS*)l, 16, 0, 0);
}

// XOR swizzle: LDS slot (row, cblk) holds global (row, cblk ^ ((row>>1)&3)).

// ---------------- router: scores = x @ rw^T, top-2 (NO atomics) -------------
__global__ __launch_bounds__(256) void k_router(const float* __restrict__ x,
    const float* __restrict__ rw, int* __restrict__ topki, float* __restrict__ topkw) {
  int wave = threadIdx.x >> 6, lane = threadIdx.x & 63;
  int t = blockIdx.x * 4 + wave;
  float acc[NE];
#pragma unroll
  for (int e = 0; e < NE; e++) acc[e] = 0.f;
  const float* xr = x + (size_t)t * HIDDEN;
  for (int i = lane; i < HIDDEN; i += 64) {
    float xv = xr[i];
#pragma unroll
    for (int e = 0; e < NE; e++) acc[e] += xv * rw[e * HIDDEN + i];
  }
#pragma unroll
  for (int e = 0; e < NE; e++) {
    float v = acc[e];
    for (int off = 32; off > 0; off >>= 1) v += __shfl_down(v, off, 64);
    acc[e] = v;
  }
  if (lane == 0) {
    int b0 = 0; float s0 = acc[0];
#pragma unroll
    for (int e = 1; e < NE; e++) if (acc[e] > s0) { s0 = acc[e]; b0 = e; }
    int b1 = -1; float s1 = -3.0e38f;
#pragma unroll
    for (int e = 0; e < NE; e++) if (e != b0 && acc[e] > s1) { s1 = acc[e]; b1 = e; }
    float w0 = 1.f / (1.f + __expf(s1 - s0));
    topki[t * 2] = b0; topki[t * 2 + 1] = b1;
    topkw[t * 2] = w0; topkw[t * 2 + 1] = 1.f - w0;
  }
}

// --------------- per-block expert histogram (LDS atomics only) -------------
__global__ __launch_bounds__(256) void k_hist(const int* __restrict__ topki,
    int* __restrict__ blockcnt) {
  __shared__ int h[NE];
  int tid = threadIdx.x, b = blockIdx.x;
  if (tid < NE) h[tid] = 0;
  __syncthreads();
  int t = b * 256 + tid;
#pragma unroll
  for (int k = 0; k < 2; k++) atomicAdd(&h[topki[t * 2 + k]], 1);
  __syncthreads();
  if (tid < NE) blockcnt[b * NE + tid] = h[tid];
}

// --------------- offsets (padded to 128), per-block bases, pad fill --------
__global__ __launch_bounds__(256) void k_offsets(const int* __restrict__ blockcnt,
    int* __restrict__ ctrl, int* __restrict__ base, int* __restrict__ tok) {
  __shared__ int counts[NE], off[NE];
  int tid = threadIdx.x;
  if (tid < NE) {
    int c = 0;
    for (int b = 0; b < 16; b++) c += blockcnt[b * NE + tid];
    counts[tid] = c;
  }
  __syncthreads();
  if (tid == 0) {
    int run = 0;
    for (int e = 0; e < NE; e++) {
      ctrl[e] = counts[e];
      ctrl[16 + e] = run;
      off[e] = run;
      run += (counts[e] + 127) & ~127;
    }
    ctrl[24] = run;
  }
  __syncthreads();
  if (tid < 128) {
    int b = tid >> 3, e = tid & 7;
    int p = off[e];
    for (int b2 = 0; b2 < b; b2++) p += blockcnt[b2 * NE + e];
    base[tid] = p;
  }
  for (int e = 0; e < NE; e++) {
    int c = counts[e], pc = (c + 127) & ~127;
    for (int i = c + tid; i < pc; i += 256) tok[off[e] + i] = -1;
  }
}

// --------------- scatter: LDS counters seeded from per-block bases ---------
__global__ __launch_bounds__(256) void k_scatter(const int* __restrict__ topki,
    const int* __restrict__ base, int* __restrict__ tok, int* __restrict__ slots) {
  __shared__ int cnt[NE];
  int tid = threadIdx.x, b = blockIdx.x;
  if (tid < NE) cnt[tid] = base[b * NE + tid];
  __syncthreads();
  int t = b * 256 + tid;
#pragma unroll
  for (int k = 0; k < 2; k++) {
    int e = topki[t * 2 + k];
    int p = atomicAdd(&cnt[e], 1);
    tok[p] = t;
    slots[t * 2 + k] = p;
  }
}

// --------------- gather x rows (fp32 -> bf16), zero pad rows ---------------
__global__ __launch_bounds__(256) void k_gather(const float* __restrict__ x,
    const int* __restrict__ ctrl, const int* __restrict__ tok,
    unsigned short* __restrict__ xg) {
  int s = blockIdx.x;
  if (s >= ctrl[24]) return;
  int t = tok[s];
  int c = threadIdx.x * 4;
  unsigned short* dst = xg + (size_t)s * HIDDEN + c;
  if (t < 0) {
    uint2 z; z.x = 0u; z.y = 0u;
    *reinterpret_cast<uint2*>(dst) = z;
  } else {
    float4 v = *reinterpret_cast<const float4*>(x + (size_t)t * HIDDEN + c);
    uint2 o;
    o.x = pack2(f2bf(v.x), f2bf(v.y));
    o.y = pack2(f2bf(v.z), f2bf(v.w));
    *reinterpret_cast<uint2*>(dst) = o;
  }
}

// --------------- int4 dequant -> bf16 (generic for w1/w2) ------------------
__global__ __launch_bounds__(256) void k_deq(const int* __restrict__ w,
    const float* __restrict__ sc, unsigned short* __restrict__ wd,
    int i32_log2, int scale_pr) {
  int gid = blockIdx.x * 256 + threadIdx.x;
  int i4 = gid * 4;
  int r = i4 >> i32_log2;
  int i = i4 & ((1 << i32_log2) - 1);
  float s = sc[r * scale_pr + (i >> 6)];
  int4 p = *reinterpret_cast<const int4*>(w + (size_t)i4);
  int pv[4] = { p.x, p.y, p.z, p.w };
  uint4 o;
  unsigned int ov[4];
#pragma unroll
  for (int j = 0; j < 4; j++) {
    float lo = (float)((pv[j] & 15) - 8) * s;
    float hi = (float)(((pv[j] >> 4) & 15) - 8) * s;
    ov[j] = pack2(f2bf(lo), f2bf(hi));
  }
  o.x = ov[0]; o.y = ov[1]; o.z = ov[2]; o.w = ov[3];
  *reinterpret_cast<uint4*>(wd + ((size_t)r << (i32_log2 + 1)) + 2 * i) = o;
}

// --------------- GEMM1: h = xg @ w1^T, fused silu(gate)*up -> a (bf16) -----
__global__ __launch_bounds__(256) void k_gemm1(
    const unsigned short* __restrict__ xg, const unsigned short* __restrict__ w1d,
    const int* __restrict__ ctrl, unsigned short* __restrict__ a_out) {
  __shared__ unsigned short sA[128 * 32];   // 8 KB
  __shared__ unsigned short sBg[64 * 32];   // 4 KB
  __shared__ unsigned short sBu[64 * 32];   // 4 KB
  int e = blockIdx.z;
  int padcnt = (ctrl[e] + 127) & ~127;
  int mt = blockIdx.y;
  if (mt * 128 >= padcnt) return;
  int row0 = ctrl[16 + e] + mt * 128;
  int n0 = blockIdx.x * 64;
  int tid = threadIdx.x;
  int wave = tid >> 6, lane = tid & 63;
  int ln = lane & 15, quad = lane >> 4;
  int wr = (wave & 1) * 64, wc = (wave >> 1) * 32;

  int srow = tid >> 2, scblk = tid & 3;
  int scol = (scblk ^ ((srow >> 1) & 3)) * 8;
  const unsigned short* gA0 = xg + (size_t)(row0 + srow) * HIDDEN + scol;
  const unsigned short* gA1 = gA0 + (size_t)64 * HIDDEN;
  const unsigned short* gBg = w1d + ((size_t)e * 4096 + n0 + srow) * HIDDEN + scol;
  const unsigned short* gBu = gBg + (size_t)INTER * HIDDEN;
  unsigned short* lA0 = sA + tid * 8;
  unsigned short* lA1 = sA + 64 * 32 + tid * 8;
  unsigned short* lBg = sBg + tid * 8;
  unsigned short* lBu = sBu + tid * 8;

  f32x4 aG[4][2] = {}, aU[4][2] = {};
  for (int k0 = 0; k0 < HIDDEN; k0 += 32) {
    __syncthreads();
    gload16(gA0 + k0, lA0);
    gload16(gA1 + k0, lA1);
    gload16(gBg + k0, lBg);
    gload16(gBu + k0, lBu);
    __syncthreads();
    bf16x8 af[4], bg[2], bu[2];
#pragma unroll
    for (int m = 0; m < 4; m++) {
      int ar = wr + m * 16 + ln;
      af[m] = *reinterpret_cast<const bf16x8*>(&sA[ar * 32 + (quad ^ ((ar >> 1) & 3)) * 8]);
    }
#pragma unroll
    for (int n = 0; n < 2; n++) {
      int br = wc + n * 16 + ln;
      int bo = br * 32 + (quad ^ ((br >> 1) & 3)) * 8;
      bg[n] = *reinterpret_cast<const bf16x8*>(&sBg[bo]);
      bu[n] = *reinterpret_cast<const bf16x8*>(&sBu[bo]);
    }
#pragma unroll
    for (int m = 0; m < 4; m++)
#pragma unroll
      for (int n = 0; n < 2; n++) {
        aG[m][n] = __builtin_amdgcn_mfma_f32_16x16x32_bf16(af[m], bg[n], aG[m][n], 0, 0, 0);
        aU[m][n] = __builtin_amdgcn_mfma_f32_16x16x32_bf16(af[m], bu[n], aU[m][n], 0, 0, 0);
      }
  }
#pragma unroll
  for (int m = 0; m < 4; m++)
#pragma unroll
    for (int n = 0; n < 2; n++) {
      int col = n0 + wc + n * 16 + ln;
#pragma unroll
      for (int r = 0; r < 4; r++) {
        float g = aG[m][n][r], u = aU[m][n][r];
        float act = (g / (1.f + __expf(-g))) * u;
        int row = row0 + wr + m * 16 + quad * 4 + r;
        a_out[(size_t)row * INTER + col] = f2bf(act);
      }
    }
}

// --------------- GEMM2: y[slot] = a @ w2^T (bf16, plain stores) ------------
__global__ __launch_bounds__(256) void k_gemm2(
    const unsigned short* __restrict__ a_in, const unsigned short* __restrict__ w2d,
    const int* __restrict__ ctrl, unsigned short* __restrict__ y) {
  __shared__ unsigned short sA[128 * 32];   // 8 KB
  __shared__ unsigned short sB[128 * 32];   // 8 KB
  int e = blockIdx.z;
  int padcnt = (ctrl[e] + 127) & ~127;
  int mt = blockIdx.y;
  if (mt * 128 >= padcnt) return;
  int row0 = ctrl[16 + e] + mt * 128;
  int n0 = blockIdx.x * 128;
  int tid = threadIdx.x;
  int wave = tid >> 6, lane = tid & 63;
  int ln = lane & 15, quad = lane >> 4;
  int wr = (wave & 1) * 64, wc = (wave >> 1) * 64;

  int srow = tid >> 2, scblk = tid & 3;
  int scol = (scblk ^ ((srow >> 1) & 3)) * 8;
  const unsigned short* gA0 = a_in + (size_t)(row0 + srow) * INTER + scol;
  const unsigned short* gA1 = gA0 + (size_t)64 * INTER;
  const unsigned short* gB0 = w2d + ((size_t)e * 1024 + n0 + srow) * INTER + scol;
  const unsigned short* gB1 = gB0 + (size_t)64 * INTER;
  unsigned short* lA0 = sA + tid * 8;
  unsigned short* lA1 = sA + 64 * 32 + tid * 8;
  unsigned short* lB0 = sB + tid * 8;
  unsigned short* lB1 = sB + 64 * 32 + tid * 8;

  f32x4 acc[4][4] = {};
  for (int k0 = 0; k0 < INTER; k0 += 32) {
    __syncthreads();
    gload16(gA0 + k0, lA0);
    gload16(gA1 + k0, lA1);
    gload16(gB0 + k0, lB0);
    gload16(gB1 + k0, lB1);
    __syncthreads();
    bf16x8 af[4], bf_[4];
#pragma unroll
    for (int m = 0; m < 4; m++) {
      int ar = wr + m * 16 + ln;
      af[m] = *reinterpret_cast<const bf16x8*>(&sA[ar * 32 + (quad ^ ((ar >> 1) & 3)) * 8]);
    }
#pragma unroll
    for (int n = 0; n < 4; n++) {
      int br = wc + n * 16 + ln;
      bf_[n] = *reinterpret_cast<const bf16x8*>(&sB[br * 32 + (quad ^ ((br >> 1) & 3)) * 8]);
    }
#pragma unroll
    for (int m = 0; m < 4; m++)
#pragma unroll
      for (int n = 0; n < 4; n++)
        acc[m][n] = __builtin_amdgcn_mfma_f32_16x16x32_bf16(af[m], bf_[n], acc[m][n], 0, 0, 0);
  }
#pragma unroll
  for (int m = 0; m < 4; m++)
#pragma unroll
    for (int n = 0; n < 4; n++) {
      int col = n0 + wc + n * 16 + ln;
#pragma unroll
      for (int r = 0; r < 4; r++) {
        int row = row0 + wr + m * 16 + quad * 4 + r;
        y[(size_t)row * HIDDEN + col] = f2bf(acc[m][n][r]);
      }
    }
}

// --------------- combine: out[t] = g0*y[s0] + g1*y[s1] ---------------------
__global__ __launch_bounds__(256) void k_combine(const unsigned short* __restrict__ y,
    const int* __restrict__ slots, const float* __restrict__ topkw,
    float* __restrict__ out) {
  int t = blockIdx.x;
  int c = threadIdx.x * 4;
  int s0 = slots[t * 2], s1 = slots[t * 2 + 1];
  float g0 = topkw[t * 2], g1 = topkw[t * 2 + 1];
  uint2 va = *reinterpret_cast<const uint2*>(y + (size_t)s0 * HIDDEN + c);
  uint2 vb = *reinterpret_cast<const uint2*>(y + (size_t)s1 * HIDDEN + c);
  float4 o;
  o.x = g0 * bf2f(va.x & 0xffffu) + g1 * bf2f(vb.x & 0xffffu);
  o.y = g0 * bf2f(va.x >> 16)     + g1 * bf2f(vb.x >> 16);
  o.z = g0 * bf2f(va.y & 0xffffu) + g1 * bf2f(vb.y & 0xffffu);
  o.w = g0 * bf2f(va.y >> 16)     + g1 * bf2f(vb.y >> 16);
  *reinterpret_cast<float4*>(out + (size_t)t * HIDDEN + c) = o;
}

extern "C" void kernel_launch(void* const* d_in, const int* in_sizes, int n_in,
                              void* d_out, int out_size, void* d_ws, size_t ws_size,
                              hipStream_t stream) {
  const float* x   = (const float*)d_in[0];
  const float* rw  = (const float*)d_in[1];
  const int*   w1  = (const int*)d_in[2];
  const float* w1s = (const float*)d_in[3];
  const int*   w2  = (const int*)d_in[4];
  const float* w2s = (const float*)d_in[5];
  float* out = (float*)d_out;
  char* ws = (char*)d_ws;

  int*   topki = (int*)(ws + OFF_TOPKI);
  float* topkw = (float*)(ws + OFF_TOPKW);
  int*   ctrl  = (int*)(ws + OFF_CTRL);
  int*   tok   = (int*)(ws + OFF_TOK);
  int*   slots = (int*)(ws + OFF_SLOT);
  int*   bc    = (int*)(ws + OFF_BC);
  int*   base  = (int*)(ws + OFF_BASE);
  unsigned short* xg  = (unsigned short*)(ws + OFF_XG);  // aliased as y after gemm1
  unsigned short* a   = (unsigned short*)(ws + OFF_A);
  unsigned short* w1d = (unsigned short*)(ws + OFF_W1D);
  unsigned short* w2d = (unsigned short*)(ws + OFF_W2D);

  k_router<<<TOKENS / 4, 256, 0, stream>>>(x, rw, topki, topkw);
  k_hist<<<16, 256, 0, stream>>>(topki, bc);
  k_offsets<<<1, 256, 0, stream>>>(bc, ctrl, base, tok);
  k_scatter<<<16, 256, 0, stream>>>(topki, base, tok, slots);
  k_gather<<<MAXROWS, 256, 0, stream>>>(x, ctrl, tok, xg);
  k_deq<<<16384, 256, 0, stream>>>(w1, w1s, w1d, 9, 8);
  k_deq<<<8192, 256, 0, stream>>>(w2, w2s, w2d, 10, 16);
  dim3 g1(INTER / 64, MAXROWS / 128, NE);
  k_gemm1<<<g1, 256, 0, stream>>>(xg, w1d, ctrl, a);
  dim3 g2(HIDDEN / 128, MAXROWS / 128, NE);
  k_gemm2<<<g2, 256, 0, stream>>>(a, w2d, ctrl, xg /* y aliases xg */);
  k_combine<<<TOKENS, 256, 0, stream>>>(xg, slots, topkw, out);
}